// Round 1
// baseline (522.584 us; speedup 1.0000x reference)
//
#include <hip/hip_runtime.h>
#include <stdint.h>

#define M_DIM 8192
#define K_DIM 4096
#define O_DIM 4096
#define NWORDS 128

#define BM 128
#define BN 128
#define BK 32

typedef __attribute__((ext_vector_type(8))) short bf16x8;
typedef __attribute__((ext_vector_type(4))) float f32x4;

__device__ __forceinline__ unsigned f32_to_bf16u(float f) {
  union { float f; unsigned u; } v; v.f = f;
  return (v.u + 0x7FFFu + ((v.u >> 16) & 1u)) >> 16;   // round-to-nearest-even
}

__device__ __forceinline__ unsigned pack_bf16x2(float lo, float hi) {
  return f32_to_bf16u(lo) | (f32_to_bf16u(hi) << 16);
}

// ---- phase 1: x fp32 -> bf16 ------------------------------------------------
__global__ __launch_bounds__(256) void cvt_x_kernel(const float* __restrict__ x,
                                                    unsigned short* __restrict__ xb) {
  long i = ((long)blockIdx.x * 256 + threadIdx.x) * 8;
  const float4 a = *(const float4*)(x + i);
  const float4 b = *(const float4*)(x + i + 4);
  uint4 o;
  o.x = pack_bf16x2(a.x, a.y);
  o.y = pack_bf16x2(a.z, a.w);
  o.z = pack_bf16x2(b.x, b.y);
  o.w = pack_bf16x2(b.z, b.w);
  *(uint4*)(xb + i) = o;
}

// ---- phase 2: ternary bitpack -> bf16 W[O][K] -------------------------------
__global__ __launch_bounds__(256) void unpack_w_kernel(const unsigned* __restrict__ nz,
                                                       const unsigned* __restrict__ sgn,
                                                       unsigned short* __restrict__ wb) {
  const int idx = blockIdx.x * 256 + threadIdx.x;   // word index in [0, O*NWORDS)
  const unsigned n = nz[idx];
  const unsigned s = sgn[idx];
  unsigned out[16];
#pragma unroll
  for (int p = 0; p < 16; ++p) {
    const int j0 = 2 * p, j1 = 2 * p + 1;
    // bf16 bit patterns: +1.0 = 0x3F80, -1.0 = 0xBF80, 0.0 = 0x0000
    unsigned lo = ((n >> j0) & 1u) ? (0x3F80u | (((s >> j0) & 1u) << 15)) : 0u;
    unsigned hi = ((n >> j1) & 1u) ? (0x3F80u | (((s >> j1) & 1u) << 15)) : 0u;
    out[p] = lo | (hi << 16);
  }
  uint4* dst = (uint4*)(wb + (long)idx * 32);
#pragma unroll
  for (int q = 0; q < 4; ++q)
    dst[q] = make_uint4(out[4 * q], out[4 * q + 1], out[4 * q + 2], out[4 * q + 3]);
}

// ---- phase 3: bf16 GEMM (m97-style), C = A * B^T, fused alpha/bias ----------
// A: [M,K] bf16 row-major. B: [O,K] bf16 row-major (i.e. B^T input).
__global__ __launch_bounds__(256) void gemm_kernel(const unsigned short* __restrict__ A,
                                                   const unsigned short* __restrict__ B,
                                                   const float* __restrict__ bias,
                                                   const float* __restrict__ alpha,
                                                   float* __restrict__ C) {
  __shared__ unsigned short lA[BM * BK];   // 8 KiB, unpadded (global_load_lds constraint)
  __shared__ unsigned short lB[BN * BK];   // 8 KiB

  const int tid  = threadIdx.x;
  const int lane = tid & 63;
  const int wave = tid >> 6;
  const int mBlk = blockIdx.y * BM;
  const int nBlk = blockIdx.x * BN;

  // staging: tile = 8192 B = 512 x 16-B chunks; thread covers chunks tid, tid+256.
  // chunk byte offset o -> row = o>>6, elem col = (o&63)>>1. Per wave: contiguous
  // 1 KiB at wave-uniform base + lane*16  (m104 layout constraint satisfied).
  const int o0 = tid * 16;
  const int o1 = o0 + 4096;
  const int r0 = o0 >> 6, c0 = (o0 & 63) >> 1;
  const int r1 = o1 >> 6, c1 = (o1 & 63) >> 1;

  const unsigned short* gA0 = A + (long)(mBlk + r0) * K_DIM + c0;
  const unsigned short* gA1 = A + (long)(mBlk + r1) * K_DIM + c1;
  const unsigned short* gB0 = B + (long)(nBlk + r0) * K_DIM + c0;
  const unsigned short* gB1 = B + (long)(nBlk + r1) * K_DIM + c1;

  char* lAc = (char*)lA;
  char* lBc = (char*)lB;

  // wave 2x2 over the 128x128 tile: each wave owns 64x64 = 4x4 MFMA tiles
  const int wm = (wave >> 1) * 64;
  const int wn = (wave & 1) * 64;
  const int fr = lane & 15;   // A row / B col within 16-tile
  const int fq = lane >> 4;   // k-quad

  f32x4 acc[4][4] = {};

  for (int kt = 0; kt < K_DIM; kt += BK) {
    __builtin_amdgcn_global_load_lds((const __attribute__((address_space(1))) void*)(gA0 + kt),
                                     (__attribute__((address_space(3))) void*)(lAc + o0), 16, 0, 0);
    __builtin_amdgcn_global_load_lds((const __attribute__((address_space(1))) void*)(gA1 + kt),
                                     (__attribute__((address_space(3))) void*)(lAc + o1), 16, 0, 0);
    __builtin_amdgcn_global_load_lds((const __attribute__((address_space(1))) void*)(gB0 + kt),
                                     (__attribute__((address_space(3))) void*)(lBc + o0), 16, 0, 0);
    __builtin_amdgcn_global_load_lds((const __attribute__((address_space(1))) void*)(gB1 + kt),
                                     (__attribute__((address_space(3))) void*)(lBc + o1), 16, 0, 0);
    __syncthreads();   // compiler emits vmcnt(0) drain before s_barrier

    bf16x8 af[4], bfv[4];
#pragma unroll
    for (int t = 0; t < 4; ++t) {
      af[t]  = *(const bf16x8*)(lA + (wm + t * 16 + fr) * BK + fq * 8);   // ds_read_b128
      bfv[t] = *(const bf16x8*)(lB + (wn + t * 16 + fr) * BK + fq * 8);
    }
#pragma unroll
    for (int tm = 0; tm < 4; ++tm)
#pragma unroll
      for (int tn = 0; tn < 4; ++tn)
        acc[tm][tn] = __builtin_amdgcn_mfma_f32_16x16x32_bf16(af[tm], bfv[tn], acc[tm][tn], 0, 0, 0);
    __syncthreads();
  }

  // epilogue: C[m][n] = acc * alpha[n] + bias[n]
  // C/D layout (verified m89/m91): col = lane&15, row = (lane>>4)*4 + reg
#pragma unroll
  for (int tn = 0; tn < 4; ++tn) {
    const int n = nBlk + wn + tn * 16 + fr;
    const float al = alpha[n];
    const float bi = bias[n];
#pragma unroll
    for (int tm = 0; tm < 4; ++tm) {
      const int mBase = mBlk + wm + tm * 16 + fq * 4;
#pragma unroll
      for (int r = 0; r < 4; ++r)
        C[(long)(mBase + r) * O_DIM + n] = acc[tm][tn][r] * al + bi;
    }
  }
}

// ---- fallback (ws too small): slow but correct fp32 path --------------------
__global__ __launch_bounds__(256) void fallback_kernel(const float* __restrict__ x,
                                                       const unsigned* __restrict__ nz,
                                                       const unsigned* __restrict__ sgn,
                                                       const float* __restrict__ bias,
                                                       const float* __restrict__ alpha,
                                                       float* __restrict__ y) {
  long gid = (long)blockIdx.x * 256 + threadIdx.x;
  int o = (int)(gid % O_DIM);
  long m = gid / O_DIM;
  const float* xr = x + m * K_DIM;
  float s = 0.f;
  for (int w = 0; w < NWORDS; ++w) {
    unsigned n = nz[o * NWORDS + w];
    unsigned g = sgn[o * NWORDS + w];
    for (int j = 0; j < 32; ++j) {
      if ((n >> j) & 1u) {
        float v = xr[w * 32 + j];
        s += ((g >> j) & 1u) ? -v : v;
      }
    }
  }
  y[gid] = s * alpha[o] + bias[o];
}

extern "C" void kernel_launch(void* const* d_in, const int* in_sizes, int n_in,
                              void* d_out, int out_size, void* d_ws, size_t ws_size,
                              hipStream_t stream) {
  const float*    x     = (const float*)d_in[0];
  const unsigned* nz    = (const unsigned*)d_in[1];
  const unsigned* sgn   = (const unsigned*)d_in[2];
  const float*    bias  = (const float*)d_in[3];
  const float*    alpha = (const float*)d_in[4];
  float*          y     = (float*)d_out;

  const size_t xb_bytes = (size_t)M_DIM * K_DIM * 2;   // 64 MiB
  const size_t wb_bytes = (size_t)O_DIM * K_DIM * 2;   // 32 MiB

  if (ws_size >= xb_bytes + wb_bytes) {
    unsigned short* xb = (unsigned short*)d_ws;
    unsigned short* wb = (unsigned short*)((char*)d_ws + xb_bytes);

    cvt_x_kernel<<<(M_DIM * (long)K_DIM) / (8 * 256), 256, 0, stream>>>(x, xb);
    unpack_w_kernel<<<(O_DIM * NWORDS) / 256, 256, 0, stream>>>(nz, sgn, wb);
    dim3 grid(O_DIM / BN, M_DIM / BM);
    gemm_kernel<<<grid, 256, 0, stream>>>(xb, wb, bias, alpha, y);
  } else {
    fallback_kernel<<<(long)M_DIM * O_DIM / 256, 256, 0, stream>>>(x, nz, sgn, bias, alpha, y);
  }
}

// Round 3
// 498.390 us; speedup vs baseline: 1.0485x; 1.0485x over previous
//
#include <hip/hip_runtime.h>
#include <stdint.h>

#define M_DIM 8192
#define K_DIM 4096
#define O_DIM 4096
#define NWORDS 128

#define BM 128
#define BN 128
#define BK 64

typedef __attribute__((ext_vector_type(8))) short bf16x8;
typedef __attribute__((ext_vector_type(4))) float f32x4;
typedef __attribute__((ext_vector_type(4))) float fvec4;
typedef __attribute__((ext_vector_type(4))) unsigned uvec4;

__device__ __forceinline__ unsigned f32_to_bf16u(float f) {
  union { float f; unsigned u; } v; v.f = f;
  return (v.u + 0x7FFFu + ((v.u >> 16) & 1u)) >> 16;   // round-to-nearest-even
}

__device__ __forceinline__ unsigned pack_bf16x2(float lo, float hi) {
  return f32_to_bf16u(lo) | (f32_to_bf16u(hi) << 16);
}

// ---- phase 1: x fp32 -> bf16, 16 elems/thread, nontemporal reads ------------
__global__ __launch_bounds__(256) void cvt_x_kernel(const fvec4* __restrict__ x,
                                                    uvec4* __restrict__ xb) {
  const long t = (long)blockIdx.x * 256 + threadIdx.x;
  const fvec4 a = __builtin_nontemporal_load(x + 4 * t + 0);
  const fvec4 b = __builtin_nontemporal_load(x + 4 * t + 1);
  const fvec4 c = __builtin_nontemporal_load(x + 4 * t + 2);
  const fvec4 d = __builtin_nontemporal_load(x + 4 * t + 3);
  uvec4 o0, o1;
  o0.x = pack_bf16x2(a.x, a.y);  o0.y = pack_bf16x2(a.z, a.w);
  o0.z = pack_bf16x2(b.x, b.y);  o0.w = pack_bf16x2(b.z, b.w);
  o1.x = pack_bf16x2(c.x, c.y);  o1.y = pack_bf16x2(c.z, c.w);
  o1.z = pack_bf16x2(d.x, d.y);  o1.w = pack_bf16x2(d.z, d.w);
  xb[2 * t] = o0;
  xb[2 * t + 1] = o1;
}

// ---- phase 2: ternary bitpack -> bf16 W[O][K] -------------------------------
__global__ __launch_bounds__(256) void unpack_w_kernel(const unsigned* __restrict__ nz,
                                                       const unsigned* __restrict__ sgn,
                                                       unsigned short* __restrict__ wb) {
  const int idx = blockIdx.x * 256 + threadIdx.x;   // word index in [0, O*NWORDS)
  const unsigned n = nz[idx];
  const unsigned s = sgn[idx];
  unsigned out[16];
#pragma unroll
  for (int p = 0; p < 16; ++p) {
    const int j0 = 2 * p, j1 = 2 * p + 1;
    unsigned lo = ((n >> j0) & 1u) ? (0x3F80u | (((s >> j0) & 1u) << 15)) : 0u;
    unsigned hi = ((n >> j1) & 1u) ? (0x3F80u | (((s >> j1) & 1u) << 15)) : 0u;
    out[p] = lo | (hi << 16);
  }
  uvec4* dst = (uvec4*)(wb + (long)idx * 32);
#pragma unroll
  for (int q = 0; q < 4; ++q) {
    uvec4 v = { out[4 * q], out[4 * q + 1], out[4 * q + 2], out[4 * q + 3] };
    dst[q] = v;
  }
}

// ---- phase 3: bf16 GEMM, BK=64, XOR-swizzled LDS, fused alpha/bias ----------
// A: [M,K] bf16 row-major. B: [O,K] bf16 row-major (B^T input).
// LDS layout: chunk (row, q) of 8 bf16 stored at slot q' = q ^ (row & 7).
// global_load_lds dest stays base + lane*16 (m104 constraint); the SOURCE
// address carries the permutation. Fragment reads apply the same XOR ->
// 16 lanes of a quad spread over all 32 banks (2-way, free per m136).
__global__ __launch_bounds__(256) void gemm_kernel(const unsigned short* __restrict__ A,
                                                   const unsigned short* __restrict__ B,
                                                   const float* __restrict__ bias,
                                                   const float* __restrict__ alpha,
                                                   float* __restrict__ C) {
  __shared__ unsigned short lA[BM * BK];   // 16 KiB
  __shared__ unsigned short lB[BN * BK];   // 16 KiB

  const int tid  = threadIdx.x;
  const int lane = tid & 63;
  const int wave = tid >> 6;
  const int mBlk = blockIdx.y * BM;
  const int nBlk = blockIdx.x * BN;

  // staging: tile = 16 KiB = 1024 x 16-B chunks; thread covers 4 chunks.
  int oArr[4];
  const unsigned short *gA[4], *gB[4];
#pragma unroll
  for (int j = 0; j < 4; ++j) {
    const int oj = tid * 16 + j * 4096;       // LDS byte offset (contig per wave)
    const int r  = oj >> 7;                   // row (128 B per row)
    const int qp = (oj >> 4) & 7;             // LDS chunk slot within row
    const int q  = qp ^ (r & 7);              // global chunk index (swizzle)
    gA[j] = A + (long)(mBlk + r) * K_DIM + q * 8;
    gB[j] = B + (long)(nBlk + r) * K_DIM + q * 8;
    oArr[j] = oj;
  }
  char* lAc = (char*)lA;
  char* lBc = (char*)lB;

  // wave 2x2 over 128x128: each wave owns 64x64 = 4x4 MFMA tiles
  const int wm = (wave >> 1) * 64;
  const int wn = (wave & 1) * 64;
  const int fr = lane & 15;   // A row / B col within 16-tile
  const int fq = lane >> 4;   // k-quad

  f32x4 acc[4][4] = {};

  for (int kt = 0; kt < K_DIM; kt += BK) {
#pragma unroll
    for (int j = 0; j < 4; ++j) {
      __builtin_amdgcn_global_load_lds((const __attribute__((address_space(1))) void*)(gA[j] + kt),
                                       (__attribute__((address_space(3))) void*)(lAc + oArr[j]), 16, 0, 0);
      __builtin_amdgcn_global_load_lds((const __attribute__((address_space(1))) void*)(gB[j] + kt),
                                       (__attribute__((address_space(3))) void*)(lBc + oArr[j]), 16, 0, 0);
    }
    __syncthreads();

#pragma unroll
    for (int kh = 0; kh < 2; ++kh) {
      bf16x8 af[4], bfv[4];
#pragma unroll
      for (int t = 0; t < 4; ++t) {
        const int rA = wm + t * 16 + fr;
        const int qA = (kh * 4 + fq) ^ (rA & 7);    // rA&7 is t-invariant (t*16 % 8 == 0)
        af[t] = *(const bf16x8*)(lA + rA * BK + qA * 8);
        const int rB = wn + t * 16 + fr;
        const int qB = (kh * 4 + fq) ^ (rB & 7);
        bfv[t] = *(const bf16x8*)(lB + rB * BK + qB * 8);
      }
#pragma unroll
      for (int tm = 0; tm < 4; ++tm)
#pragma unroll
        for (int tn = 0; tn < 4; ++tn)
          acc[tm][tn] = __builtin_amdgcn_mfma_f32_16x16x32_bf16(af[tm], bfv[tn], acc[tm][tn], 0, 0, 0);
    }
    __syncthreads();
  }

  // epilogue: C[m][n] = acc * alpha[n] + bias[n]; nontemporal (y is write-once)
  // C/D layout (verified m89/m91): col = lane&15, row = (lane>>4)*4 + reg
#pragma unroll
  for (int tn = 0; tn < 4; ++tn) {
    const int n = nBlk + wn + tn * 16 + fr;
    const float al = alpha[n];
    const float bi = bias[n];
#pragma unroll
    for (int tm = 0; tm < 4; ++tm) {
      const int mBase = mBlk + wm + tm * 16 + fq * 4;
#pragma unroll
      for (int r = 0; r < 4; ++r)
        __builtin_nontemporal_store(acc[tm][tn][r] * al + bi,
                                    C + (long)(mBase + r) * O_DIM + n);
    }
  }
}

// ---- fallback (ws too small): slow but correct fp32 path --------------------
__global__ __launch_bounds__(256) void fallback_kernel(const float* __restrict__ x,
                                                       const unsigned* __restrict__ nz,
                                                       const unsigned* __restrict__ sgn,
                                                       const float* __restrict__ bias,
                                                       const float* __restrict__ alpha,
                                                       float* __restrict__ y) {
  long gid = (long)blockIdx.x * 256 + threadIdx.x;
  int o = (int)(gid % O_DIM);
  long m = gid / O_DIM;
  const float* xr = x + m * K_DIM;
  float s = 0.f;
  for (int w = 0; w < NWORDS; ++w) {
    unsigned n = nz[o * NWORDS + w];
    unsigned g = sgn[o * NWORDS + w];
    for (int j = 0; j < 32; ++j) {
      if ((n >> j) & 1u) {
        float v = xr[w * 32 + j];
        s += ((g >> j) & 1u) ? -v : v;
      }
    }
  }
  y[gid] = s * alpha[o] + bias[o];
}

extern "C" void kernel_launch(void* const* d_in, const int* in_sizes, int n_in,
                              void* d_out, int out_size, void* d_ws, size_t ws_size,
                              hipStream_t stream) {
  const float*    x     = (const float*)d_in[0];
  const unsigned* nz    = (const unsigned*)d_in[1];
  const unsigned* sgn   = (const unsigned*)d_in[2];
  const float*    bias  = (const float*)d_in[3];
  const float*    alpha = (const float*)d_in[4];
  float*          y     = (float*)d_out;

  const size_t xb_bytes = (size_t)M_DIM * K_DIM * 2;   // 64 MiB
  const size_t wb_bytes = (size_t)O_DIM * K_DIM * 2;   // 32 MiB

  if (ws_size >= xb_bytes + wb_bytes) {
    unsigned short* xb = (unsigned short*)d_ws;
    unsigned short* wb = (unsigned short*)((char*)d_ws + xb_bytes);

    cvt_x_kernel<<<(M_DIM * (long)K_DIM) / (16 * 256), 256, 0, stream>>>((const fvec4*)x, (uvec4*)xb);
    unpack_w_kernel<<<(O_DIM * NWORDS) / 256, 256, 0, stream>>>(nz, sgn, wb);
    dim3 grid(O_DIM / BN, M_DIM / BM);
    gemm_kernel<<<grid, 256, 0, stream>>>(xb, wb, bias, alpha, y);
  } else {
    fallback_kernel<<<(long)M_DIM * O_DIM / 256, 256, 0, stream>>>(x, nz, sgn, bias, alpha, y);
  }
}

// Round 4
// 488.274 us; speedup vs baseline: 1.0703x; 1.0207x over previous
//
#include <hip/hip_runtime.h>
#include <stdint.h>

#define M_DIM 8192
#define K_DIM 4096
#define O_DIM 4096
#define NWORDS 128

#define BM 128
#define BN 128
#define BK 64

typedef __attribute__((ext_vector_type(8))) short bf16x8;
typedef __attribute__((ext_vector_type(4))) float f32x4;
typedef __attribute__((ext_vector_type(4))) float fvec4;
typedef __attribute__((ext_vector_type(4))) unsigned uvec4;
typedef __attribute__((ext_vector_type(2))) unsigned uvec2;

__device__ __forceinline__ unsigned f32_to_bf16u(float f) {
  union { float f; unsigned u; } v; v.f = f;
  return (v.u + 0x7FFFu + ((v.u >> 16) & 1u)) >> 16;   // round-to-nearest-even
}

__device__ __forceinline__ unsigned pack_bf16x2(float lo, float hi) {
  return f32_to_bf16u(lo) | (f32_to_bf16u(hi) << 16);
}

// ---- phase 1 (merged): x fp32->bf16 AND ternary unpack, one launch ----------
// Blocks [0, 8192): convert x. Fully coalesced: lane-contiguous fvec4 loads
// (16 B/lane) and uvec2 stores (8 B/lane), 4 chunks at block-stride 256.
// Blocks [8192, 16384): unpack W. 4 threads per word; thread (w, q) emits the
// 16-B chunk for bits [8q, 8q+8) -> lane-contiguous uvec4 stores.
__global__ __launch_bounds__(256) void prep_kernel(const fvec4* __restrict__ x,
                                                   uvec2* __restrict__ xb,
                                                   const unsigned* __restrict__ nz,
                                                   const unsigned* __restrict__ sgn,
                                                   unsigned short* __restrict__ wb) {
  const int b   = blockIdx.x;
  const int tid = threadIdx.x;
  if (b < 8192) {
    const long base = (long)b * 1024 + tid;
#pragma unroll
    for (int j = 0; j < 4; ++j) {
      const long g = base + j * 256;
      const fvec4 v = x[g];
      uvec2 o;
      o.x = pack_bf16x2(v.x, v.y);
      o.y = pack_bf16x2(v.z, v.w);
      xb[g] = o;
    }
  } else {
    const int i = (b - 8192) * 256 + tid;   // (word, q) pair id
    const int w = i >> 2;
    const int q = i & 3;
    const unsigned n = nz[w] >> (8 * q);
    const unsigned s = sgn[w] >> (8 * q);
    unsigned out[4];
#pragma unroll
    for (int p = 0; p < 4; ++p) {
      const int j0 = 2 * p, j1 = 2 * p + 1;
      unsigned lo = ((n >> j0) & 1u) ? (0x3F80u | (((s >> j0) & 1u) << 15)) : 0u;
      unsigned hi = ((n >> j1) & 1u) ? (0x3F80u | (((s >> j1) & 1u) << 15)) : 0u;
      out[p] = lo | (hi << 16);
    }
    uvec4 v = { out[0], out[1], out[2], out[3] };
    *(uvec4*)(wb + (long)w * 32 + q * 8) = v;   // byte addr = i*16: coalesced
  }
}

// ---- phase 2: bf16 GEMM, BK=64, XOR-swizzled LDS, fused alpha/bias ----------
// A: [M,K] bf16 row-major. B: [O,K] bf16 row-major (B^T input).
// LDS layout: chunk (row, q) of 8 bf16 stored at slot q' = q ^ (row & 7).
// global_load_lds dest stays base + lane*16 (m104 constraint); the SOURCE
// address carries the permutation. Fragment reads apply the same XOR ->
// 2-way bank aliasing only (free per m136). Verified R3: conflicts == 0.
__global__ __launch_bounds__(256) void gemm_kernel(const unsigned short* __restrict__ A,
                                                   const unsigned short* __restrict__ B,
                                                   const float* __restrict__ bias,
                                                   const float* __restrict__ alpha,
                                                   float* __restrict__ C) {
  __shared__ unsigned short lA[BM * BK];   // 16 KiB
  __shared__ unsigned short lB[BN * BK];   // 16 KiB

  const int tid  = threadIdx.x;
  const int lane = tid & 63;
  const int wave = tid >> 6;
  const int mBlk = blockIdx.y * BM;
  const int nBlk = blockIdx.x * BN;

  // staging: tile = 16 KiB = 1024 x 16-B chunks; thread covers 4 chunks.
  int oArr[4];
  const unsigned short *gA[4], *gB[4];
#pragma unroll
  for (int j = 0; j < 4; ++j) {
    const int oj = tid * 16 + j * 4096;       // LDS byte offset (contig per wave)
    const int r  = oj >> 7;                   // row (128 B per row)
    const int qp = (oj >> 4) & 7;             // LDS chunk slot within row
    const int q  = qp ^ (r & 7);              // global chunk index (swizzle)
    gA[j] = A + (long)(mBlk + r) * K_DIM + q * 8;
    gB[j] = B + (long)(nBlk + r) * K_DIM + q * 8;
    oArr[j] = oj;
  }
  char* lAc = (char*)lA;
  char* lBc = (char*)lB;

  // wave 2x2 over 128x128: each wave owns 64x64 = 4x4 MFMA tiles
  const int wm = (wave >> 1) * 64;
  const int wn = (wave & 1) * 64;
  const int fr = lane & 15;   // A row / B col within 16-tile
  const int fq = lane >> 4;   // k-quad

  f32x4 acc[4][4] = {};

  for (int kt = 0; kt < K_DIM; kt += BK) {
#pragma unroll
    for (int j = 0; j < 4; ++j) {
      __builtin_amdgcn_global_load_lds((const __attribute__((address_space(1))) void*)(gA[j] + kt),
                                       (__attribute__((address_space(3))) void*)(lAc + oArr[j]), 16, 0, 0);
      __builtin_amdgcn_global_load_lds((const __attribute__((address_space(1))) void*)(gB[j] + kt),
                                       (__attribute__((address_space(3))) void*)(lBc + oArr[j]), 16, 0, 0);
    }
    __syncthreads();

#pragma unroll
    for (int kh = 0; kh < 2; ++kh) {
      bf16x8 af[4], bfv[4];
#pragma unroll
      for (int t = 0; t < 4; ++t) {
        const int rA = wm + t * 16 + fr;
        const int qA = (kh * 4 + fq) ^ (rA & 7);    // rA&7 is t-invariant (t*16 % 8 == 0)
        af[t] = *(const bf16x8*)(lA + rA * BK + qA * 8);
        const int rB = wn + t * 16 + fr;
        const int qB = (kh * 4 + fq) ^ (rB & 7);
        bfv[t] = *(const bf16x8*)(lB + rB * BK + qB * 8);
      }
#pragma unroll
      for (int tm = 0; tm < 4; ++tm)
#pragma unroll
        for (int tn = 0; tn < 4; ++tn)
          acc[tm][tn] = __builtin_amdgcn_mfma_f32_16x16x32_bf16(af[tm], bfv[tn], acc[tm][tn], 0, 0, 0);
    }
    __syncthreads();
  }

  // epilogue: C[m][n] = acc * alpha[n] + bias[n]; nontemporal (y is write-once)
  // C/D layout (verified m89/m91): col = lane&15, row = (lane>>4)*4 + reg
#pragma unroll
  for (int tn = 0; tn < 4; ++tn) {
    const int n = nBlk + wn + tn * 16 + fr;
    const float al = alpha[n];
    const float bi = bias[n];
#pragma unroll
    for (int tm = 0; tm < 4; ++tm) {
      const int mBase = mBlk + wm + tm * 16 + fq * 4;
#pragma unroll
      for (int r = 0; r < 4; ++r)
        __builtin_nontemporal_store(acc[tm][tn][r] * al + bi,
                                    C + (long)(mBase + r) * O_DIM + n);
    }
  }
}

// ---- fallback (ws too small): slow but correct fp32 path --------------------
__global__ __launch_bounds__(256) void fallback_kernel(const float* __restrict__ x,
                                                       const unsigned* __restrict__ nz,
                                                       const unsigned* __restrict__ sgn,
                                                       const float* __restrict__ bias,
                                                       const float* __restrict__ alpha,
                                                       float* __restrict__ y) {
  long gid = (long)blockIdx.x * 256 + threadIdx.x;
  int o = (int)(gid % O_DIM);
  long m = gid / O_DIM;
  const float* xr = x + m * K_DIM;
  float s = 0.f;
  for (int w = 0; w < NWORDS; ++w) {
    unsigned n = nz[o * NWORDS + w];
    unsigned g = sgn[o * NWORDS + w];
    for (int j = 0; j < 32; ++j) {
      if ((n >> j) & 1u) {
        float v = xr[w * 32 + j];
        s += ((g >> j) & 1u) ? -v : v;
      }
    }
  }
  y[gid] = s * alpha[o] + bias[o];
}

extern "C" void kernel_launch(void* const* d_in, const int* in_sizes, int n_in,
                              void* d_out, int out_size, void* d_ws, size_t ws_size,
                              hipStream_t stream) {
  const float*    x     = (const float*)d_in[0];
  const unsigned* nz    = (const unsigned*)d_in[1];
  const unsigned* sgn   = (const unsigned*)d_in[2];
  const float*    bias  = (const float*)d_in[3];
  const float*    alpha = (const float*)d_in[4];
  float*          y     = (float*)d_out;

  const size_t xb_bytes = (size_t)M_DIM * K_DIM * 2;   // 64 MiB
  const size_t wb_bytes = (size_t)O_DIM * K_DIM * 2;   // 32 MiB

  if (ws_size >= xb_bytes + wb_bytes) {
    unsigned short* xb = (unsigned short*)d_ws;
    unsigned short* wb = (unsigned short*)((char*)d_ws + xb_bytes);

    // 8192 cvt blocks + 8192 unpack blocks, one launch
    prep_kernel<<<16384, 256, 0, stream>>>((const fvec4*)x, (uvec2*)xb, nz, sgn, wb);
    dim3 grid(O_DIM / BN, M_DIM / BM);
    gemm_kernel<<<grid, 256, 0, stream>>>(xb, wb, bias, alpha, y);
  } else {
    fallback_kernel<<<(long)M_DIM * O_DIM / 256, 256, 0, stream>>>(x, nz, sgn, bias, alpha, y);
  }
}